// Round 6
// baseline (314.534 us; speedup 1.0000x reference)
//
#include <hip/hip_runtime.h>
#include <hip/hip_bf16.h>

// Problem constants
#define B_ 4
#define S_ 2048
#define D_ 1024
#define H_ 16
#define DH_ 64
#define M_ 8192                 // B*S rows
#define NX (M_ * D_)            // 8388608 elems per activation matrix
#define NW (D_ * D_)            // 1048576 elems per weight matrix

typedef unsigned short ushort_t;
typedef __attribute__((ext_vector_type(8))) short short8;   // 8 bf16 (4 VGPRs)
typedef __attribute__((ext_vector_type(4))) float f32x4;

// ---- bf16 helpers (bit-level, RNE) ----
__device__ inline float bf2f(unsigned short u) {
  union { unsigned int i; float f; } c; c.i = ((unsigned int)u) << 16; return c.f;
}
__device__ inline unsigned short f2bf(float f) {
  union { float f_; unsigned int i; } c; c.f_ = f;
  return (unsigned short)((c.i + 0x7FFFu + ((c.i >> 16) & 1u)) >> 16);
}

// ---- async global->LDS, 16B per lane ----
typedef __attribute__((address_space(1))) void v_g;
typedef __attribute__((address_space(3))) void v_l;
__device__ inline void async16(const void* g, void* l) {
  __builtin_amdgcn_global_load_lds((const v_g*)g, (v_l*)l, 16, 0, 0);
}

// ============================================================
// Kernel A: convert 3 activation mats + 3 weight mats f32->bf16
// ============================================================
__global__ __launch_bounds__(256) void cvt6(
    const float* __restrict__ x0, const float* __restrict__ x1, const float* __restrict__ x2,
    const float* __restrict__ w0, const float* __restrict__ w1, const float* __restrict__ w2,
    ushort_t* __restrict__ xb, ushort_t* __restrict__ wb) {
  const int GX = NX / 4;   // 2^21 groups of 4 floats per activation
  const int GW = NW / 4;   // 2^18 per weight
  int g = blockIdx.x * 256 + threadIdx.x;
  const float* src; ushort_t* dst; int off;
  if (g < 3 * GX) {
    int mat = g / GX; off = (g - mat * GX) * 4;
    src = (mat == 0) ? x0 : ((mat == 1) ? x1 : x2);
    dst = xb + (size_t)mat * NX;
  } else {
    int g2 = g - 3 * GX;
    if (g2 >= 3 * GW) return;
    int mat = g2 / GW; off = (g2 - mat * GW) * 4;
    src = (mat == 0) ? w0 : ((mat == 1) ? w1 : w2);
    dst = wb + (size_t)mat * NW;
  }
  float4 v = *(const float4*)(src + off);
  ushort4 o;
  o.x = f2bf(v.x); o.y = f2bf(v.y); o.z = f2bf(v.z); o.w = f2bf(v.w);
  *(ushort4*)(dst + off) = o;
}

// ============================================================
// Kernel B: C[m,n] = sum_k A[m,k]*W[n,k] + bias[n]  (bf16 MFMA)
// 128x128 tile, BK=64, 4 waves, global_load_lds w=16 (m97 structure)
// grid = (64*8, 3); blockIdx.y selects Q/K/V
// ============================================================
__global__ __launch_bounds__(256) void gemm_qkv(
    const ushort_t* __restrict__ Xb, const ushort_t* __restrict__ Wb,
    const float* __restrict__ bQ, const float* __restrict__ bK, const float* __restrict__ bV,
    ushort_t* __restrict__ Out) {
  __shared__ __align__(16) ushort_t As[128 * 64];
  __shared__ __align__(16) ushort_t Bs[128 * 64];

  const int mat = blockIdx.y;
  const ushort_t* A  = Xb + (size_t)mat * NX;
  const ushort_t* Bg = Wb + (size_t)mat * NW;
  const float* bias = (mat == 0) ? bQ : ((mat == 1) ? bK : bV);
  ushort_t* C = Out + (size_t)mat * NX;

  const int tn = blockIdx.x & 7;        // N/128 = 8 col tiles
  const int tm = blockIdx.x >> 3;       // M/128 = 64 row tiles
  const int m0 = tm * 128, n0 = tn * 128;

  const int t = threadIdx.x;
  const int w = t >> 6, l = t & 63;
  const int wr = w >> 1, wc = w & 1;    // wave quadrant (64x64)

  // staging geometry: chunk c = i*256+t covers (row = i*32 + t>>3, col8 = (t&7)*8)
  const int r0 = t >> 3;
  const int c0 = (t & 7) << 3;
  const ushort_t* gAt = A  + (size_t)(m0 + r0) * D_ + c0;
  const ushort_t* gBt = Bg + (size_t)(n0 + r0) * D_ + c0;
  ushort_t* lAt = (ushort_t*)As + w * 512;   // + i*2048 per iteration
  ushort_t* lBt = (ushort_t*)Bs + w * 512;

  // fragment read offsets (16x16x32 bf16: lane holds row l&15, k = (l>>4)*8 .. +7)
  const int lrow = l & 15, lk = (l >> 4) << 3;
  const int aoff = (wr * 64 + lrow) * 64 + lk;
  const int boff = (wc * 64 + lrow) * 64 + lk;

  f32x4 acc[4][4];
#pragma unroll
  for (int i = 0; i < 4; i++)
#pragma unroll
    for (int j = 0; j < 4; j++) acc[i][j] = (f32x4){0.f, 0.f, 0.f, 0.f};

  for (int kt = 0; kt < 16; ++kt) {
    const int k0 = kt * 64;
#pragma unroll
    for (int i = 0; i < 4; ++i) {
      async16(gAt + (size_t)i * (32 * D_) + k0, lAt + i * 2048);
      async16(gBt + (size_t)i * (32 * D_) + k0, lBt + i * 2048);
    }
    asm volatile("s_waitcnt vmcnt(0)" ::: "memory");
    __syncthreads();

#pragma unroll
    for (int kk = 0; kk < 64; kk += 32) {
      short8 a[4], b[4];
#pragma unroll
      for (int mi = 0; mi < 4; mi++) a[mi] = *(const short8*)(As + aoff + mi * (16 * 64) + kk);
#pragma unroll
      for (int ni = 0; ni < 4; ni++) b[ni] = *(const short8*)(Bs + boff + ni * (16 * 64) + kk);
#pragma unroll
      for (int mi = 0; mi < 4; mi++)
#pragma unroll
        for (int ni = 0; ni < 4; ni++)
          acc[mi][ni] = __builtin_amdgcn_mfma_f32_16x16x32_bf16(a[mi], b[ni], acc[mi][ni], 0, 0, 0);
    }
    __syncthreads();
  }

  // epilogue: C/D layout col=lane&15, row=(lane>>4)*4+reg  (m89/m91-verified)
  const int crow0 = m0 + wr * 64 + ((l >> 4) << 2);
  const int ccol0 = n0 + wc * 64 + (l & 15);
#pragma unroll
  for (int mi = 0; mi < 4; mi++) {
#pragma unroll
    for (int ni = 0; ni < 4; ni++) {
      const int col = ccol0 + ni * 16;
      const float bv = bias[col];
      const int row = crow0 + mi * 16;
#pragma unroll
      for (int r = 0; r < 4; r++) {
        C[(size_t)(row + r) * D_ + col] = f2bf(acc[mi][ni][r] + bv);
      }
    }
  }
}

// ============================================================
// Kernel C: per-position head attention + output projection
// scores[h][t] = Q[h,:]·K[t,:] (16x16), softmax over t, +mask,
// out = attn@V, *0.125, then @Wp.T + b. One block per (b,s).
// ============================================================
__global__ __launch_bounds__(256) void attn_out(
    const ushort_t* __restrict__ QKV, const float* __restrict__ mask,
    const float* __restrict__ Wp, const float* __restrict__ Wpb,
    float* __restrict__ out) {
  __shared__ float Qs[16 * 68], Ks[16 * 68], Vs[16 * 68];
  __shared__ float Asc[16 * 17];
  __shared__ float Os[16 * 68];
  __shared__ float WpT[64 * 65];   // stride 65: conflict-free column writes

  const int p = blockIdx.x;
  const int t = threadIdx.x;
  const ushort_t* Qb = QKV;
  const ushort_t* Kb = QKV + (size_t)NX;
  const ushort_t* Vb = QKV + (size_t)2 * NX;
  const size_t base = (size_t)p * (H_ * DH_);

  // stage Q,K,V bf16 -> f32 LDS (padded stride 68)
  {
    const int idx = t * 4;
    const int h0 = idx >> 6, d0 = idx & 63;
    ushort4 q = *(const ushort4*)(Qb + base + idx);
    ushort4 k = *(const ushort4*)(Kb + base + idx);
    ushort4 v = *(const ushort4*)(Vb + base + idx);
    float* qd = Qs + h0 * 68 + d0;
    float* kd = Ks + h0 * 68 + d0;
    float* vd = Vs + h0 * 68 + d0;
    qd[0] = bf2f(q.x); qd[1] = bf2f(q.y); qd[2] = bf2f(q.z); qd[3] = bf2f(q.w);
    kd[0] = bf2f(k.x); kd[1] = bf2f(k.y); kd[2] = bf2f(k.z); kd[3] = bf2f(k.w);
    vd[0] = bf2f(v.x); vd[1] = bf2f(v.y); vd[2] = bf2f(v.z); vd[3] = bf2f(v.w);
  }
  // stage Wp transposed: WpT[e][d] = Wp[d][e]
#pragma unroll
  for (int i = 0; i < 16; ++i) {
    const int idx = i * 256 + t;          // 0..4095
    const int dr = idx >> 6, e = idx & 63;
    WpT[e * 65 + dr] = Wp[idx];
  }
  __syncthreads();

  const int h = t >> 4, tt = t & 15;

  // scores + softmax (16-lane-group shuffle reduce)
  float s = 0.f;
#pragma unroll
  for (int d = 0; d < 64; ++d) s += Qs[h * 68 + d] * Ks[tt * 68 + d];
  float mx = s;
#pragma unroll
  for (int o = 8; o >= 1; o >>= 1) mx = fmaxf(mx, __shfl_xor(mx, o, 16));
  const float ev = __expf(s - mx);
  float sm = ev;
#pragma unroll
  for (int o = 8; o >= 1; o >>= 1) sm += __shfl_xor(sm, o, 16);
  Asc[h * 17 + tt] = ev / sm + mask[h * 16 + tt];   // faithful quirk: mask AFTER softmax
  __syncthreads();

  // PV: out[h][d] = sum_t attn[h][t] * V[t][d]; scale AFTER (quirk)
  {
    const int dq = tt * 4;
    float4 o4 = {0.f, 0.f, 0.f, 0.f};
#pragma unroll
    for (int k = 0; k < 16; ++k) {
      const float a = Asc[h * 17 + k];
      o4.x += a * Vs[k * 68 + dq + 0];
      o4.y += a * Vs[k * 68 + dq + 1];
      o4.z += a * Vs[k * 68 + dq + 2];
      o4.w += a * Vs[k * 68 + dq + 3];
    }
    float* od = Os + h * 68 + dq;
    od[0] = o4.x * 0.125f; od[1] = o4.y * 0.125f;
    od[2] = o4.z * 0.125f; od[3] = o4.w * 0.125f;
  }
  __syncthreads();

  // projection: final[h][d] = sum_e Os[h][e] * Wp[d][e] + Wpb[d]
  {
    const int dq = tt * 4;
    float r0 = Wpb[dq + 0], r1 = Wpb[dq + 1], r2 = Wpb[dq + 2], r3 = Wpb[dq + 3];
#pragma unroll
    for (int e = 0; e < 64; ++e) {
      const float ov = Os[h * 68 + e];
      const float* wr = WpT + e * 65 + dq;
      r0 += ov * wr[0]; r1 += ov * wr[1]; r2 += ov * wr[2]; r3 += ov * wr[3];
    }
    float4 res = {r0, r1, r2, r3};
    *(float4*)(out + base + h * 64 + dq) = res;
  }
}

// ============================================================
extern "C" void kernel_launch(void* const* d_in, const int* in_sizes, int n_in,
                              void* d_out, int out_size, void* d_ws, size_t ws_size,
                              hipStream_t stream) {
  const float* target = (const float*)d_in[0];
  const float* source = (const float*)d_in[1];
  const float* memory = (const float*)d_in[2];
  const float* mask   = (const float*)d_in[3];
  const float* WQw = (const float*)d_in[4];
  const float* WQb = (const float*)d_in[5];
  const float* WKw = (const float*)d_in[6];
  const float* WKb = (const float*)d_in[7];
  const float* WVw = (const float*)d_in[8];
  const float* WVb = (const float*)d_in[9];
  const float* Wpw = (const float*)d_in[10];
  const float* Wpb = (const float*)d_in[11];

  // workspace layout (bytes): Xb 48MB | Wb 6MB | QKV 48MB  = ~102MB
  ushort_t* Xb  = (ushort_t*)d_ws;            // 3*NX bf16
  ushort_t* Wb  = Xb + (size_t)3 * NX;        // 3*NW bf16
  ushort_t* QKV = Wb + (size_t)3 * NW;        // 3*NX bf16
  float* outp = (float*)d_out;

  // A: convert inputs + weights to bf16
  cvt6<<<dim3((3 * NX / 4 + 3 * NW / 4) / 256), 256, 0, stream>>>(
      target, source, memory, WQw, WKw, WVw, Xb, Wb);

  // B: QKV projections (bias fused), bf16 out
  gemm_qkv<<<dim3(512, 3), 256, 0, stream>>>(Xb, Wb, WQb, WKb, WVb, QKV);

  // C: fused head-attention + final projection, f32 out
  attn_out<<<dim3(M_), 256, 0, stream>>>(QKV, mask, Wpw, Wpb, outp);
}

// Round 7
// 286.159 us; speedup vs baseline: 1.0992x; 1.0992x over previous
//
#include <hip/hip_runtime.h>
#include <hip/hip_bf16.h>

// Problem constants
#define B_ 4
#define S_ 2048
#define D_ 1024
#define H_ 16
#define DH_ 64
#define M_ 8192                 // B*S rows
#define NX (M_ * D_)            // 8388608 elems per activation matrix
#define NW (D_ * D_)            // 1048576 elems per weight matrix

typedef unsigned short ushort_t;
typedef __attribute__((ext_vector_type(8))) short short8;   // 8 bf16 (4 VGPRs)
typedef __attribute__((ext_vector_type(4))) float f32x4;

// ---- bf16 helpers (bit-level, RNE) ----
__device__ inline float bf2f(unsigned short u) {
  union { unsigned int i; float f; } c; c.i = ((unsigned int)u) << 16; return c.f;
}
__device__ inline unsigned short f2bf(float f) {
  union { float f_; unsigned int i; } c; c.f_ = f;
  return (unsigned short)((c.i + 0x7FFFu + ((c.i >> 16) & 1u)) >> 16);
}

// ---- async global->LDS, 16B per lane ----
typedef __attribute__((address_space(1))) void v_g;
typedef __attribute__((address_space(3))) void v_l;
__device__ inline void async16(const void* g, void* l) {
  __builtin_amdgcn_global_load_lds((const v_g*)g, (v_l*)l, 16, 0, 0);
}

// ============================================================
// Kernel A: convert 3 activation mats + 3 weight mats f32->bf16
// ============================================================
__global__ __launch_bounds__(256) void cvt6(
    const float* __restrict__ x0, const float* __restrict__ x1, const float* __restrict__ x2,
    const float* __restrict__ w0, const float* __restrict__ w1, const float* __restrict__ w2,
    ushort_t* __restrict__ xb, ushort_t* __restrict__ wb) {
  const int GX = NX / 4;   // 2^21 groups of 4 floats per activation
  const int GW = NW / 4;   // 2^18 per weight
  int g = blockIdx.x * 256 + threadIdx.x;
  const float* src; ushort_t* dst; int off;
  if (g < 3 * GX) {
    int mat = g / GX; off = (g - mat * GX) * 4;
    src = (mat == 0) ? x0 : ((mat == 1) ? x1 : x2);
    dst = xb + (size_t)mat * NX;
  } else {
    int g2 = g - 3 * GX;
    if (g2 >= 3 * GW) return;
    int mat = g2 / GW; off = (g2 - mat * GW) * 4;
    src = (mat == 0) ? w0 : ((mat == 1) ? w1 : w2);
    dst = wb + (size_t)mat * NW;
  }
  float4 v = *(const float4*)(src + off);
  ushort4 o;
  o.x = f2bf(v.x); o.y = f2bf(v.y); o.z = f2bf(v.z); o.w = f2bf(v.w);
  *(ushort4*)(dst + off) = o;
}

// ============================================================
// Kernel B: C[m,n] = sum_k A[m,k]*W[n,k] + bias[n]  (bf16 MFMA)
// 128x128 tile, BK=64, 4 waves, global_load_lds w=16 (m97 structure)
// grid = 1D 1536 with bijective XCD swizzle (T1): 1536 = 8 XCDs * 192.
// Consecutive swizzled ids (same XCD) share A row-panels -> per-XCD L2 reuse.
// ============================================================
__global__ __launch_bounds__(256) void gemm_qkv(
    const ushort_t* __restrict__ Xb, const ushort_t* __restrict__ Wb,
    const float* __restrict__ bQ, const float* __restrict__ bK, const float* __restrict__ bV,
    ushort_t* __restrict__ Out) {
  __shared__ __align__(16) ushort_t As[128 * 64];
  __shared__ __align__(16) ushort_t Bs[128 * 64];

  // T1 XCD swizzle: hw block o lands on XCD (o%8); give each XCD a
  // contiguous run of 192 logical tiles (24 A-panels, each reused 8x).
  const int o = blockIdx.x;
  const int sw = (o & 7) * 192 + (o >> 3);   // bijective on [0,1536)
  const int mat = sw >> 9;                   // 512 tiles per matrix
  const int w_  = sw & 511;
  const int tn = w_ & 7;        // N/128 = 8 col tiles (share A panel)
  const int tm = w_ >> 3;       // M/128 = 64 row tiles

  const ushort_t* A  = Xb + (size_t)mat * NX;
  const ushort_t* Bg = Wb + (size_t)mat * NW;
  const float* bias = (mat == 0) ? bQ : ((mat == 1) ? bK : bV);
  ushort_t* C = Out + (size_t)mat * NX;

  const int m0 = tm * 128, n0 = tn * 128;

  const int t = threadIdx.x;
  const int w = t >> 6, l = t & 63;
  const int wr = w >> 1, wc = w & 1;    // wave quadrant (64x64)

  // staging geometry: chunk c = i*256+t covers (row = i*32 + t>>3, col8 = (t&7)*8)
  const int r0 = t >> 3;
  const int c0 = (t & 7) << 3;
  const ushort_t* gAt = A  + (size_t)(m0 + r0) * D_ + c0;
  const ushort_t* gBt = Bg + (size_t)(n0 + r0) * D_ + c0;
  ushort_t* lAt = (ushort_t*)As + w * 512;   // + i*2048 per iteration
  ushort_t* lBt = (ushort_t*)Bs + w * 512;

  // fragment read offsets (16x16x32 bf16: lane holds row l&15, k = (l>>4)*8 .. +7)
  const int lrow = l & 15, lk = (l >> 4) << 3;
  const int aoff = (wr * 64 + lrow) * 64 + lk;
  const int boff = (wc * 64 + lrow) * 64 + lk;

  f32x4 acc[4][4];
#pragma unroll
  for (int i = 0; i < 4; i++)
#pragma unroll
    for (int j = 0; j < 4; j++) acc[i][j] = (f32x4){0.f, 0.f, 0.f, 0.f};

  for (int kt = 0; kt < 16; ++kt) {
    const int k0 = kt * 64;
#pragma unroll
    for (int i = 0; i < 4; ++i) {
      async16(gAt + (size_t)i * (32 * D_) + k0, lAt + i * 2048);
      async16(gBt + (size_t)i * (32 * D_) + k0, lBt + i * 2048);
    }
    asm volatile("s_waitcnt vmcnt(0)" ::: "memory");
    __syncthreads();

#pragma unroll
    for (int kk = 0; kk < 64; kk += 32) {
      short8 a[4], b[4];
#pragma unroll
      for (int mi = 0; mi < 4; mi++) a[mi] = *(const short8*)(As + aoff + mi * (16 * 64) + kk);
#pragma unroll
      for (int ni = 0; ni < 4; ni++) b[ni] = *(const short8*)(Bs + boff + ni * (16 * 64) + kk);
#pragma unroll
      for (int mi = 0; mi < 4; mi++)
#pragma unroll
        for (int ni = 0; ni < 4; ni++)
          acc[mi][ni] = __builtin_amdgcn_mfma_f32_16x16x32_bf16(a[mi], b[ni], acc[mi][ni], 0, 0, 0);
    }
    __syncthreads();
  }

  // epilogue: C/D layout col=lane&15, row=(lane>>4)*4+reg  (m89/m91-verified)
  const int crow0 = m0 + wr * 64 + ((l >> 4) << 2);
  const int ccol0 = n0 + wc * 64 + (l & 15);
#pragma unroll
  for (int mi = 0; mi < 4; mi++) {
#pragma unroll
    for (int ni = 0; ni < 4; ni++) {
      const int col = ccol0 + ni * 16;
      const float bv = bias[col];
      const int row = crow0 + mi * 16;
#pragma unroll
      for (int r = 0; r < 4; r++) {
        C[(size_t)(row + r) * D_ + col] = f2bf(acc[mi][ni][r] + bv);
      }
    }
  }
}

// ============================================================
// Kernel C: per-position head attention + output projection
// scores[h][t] = Q[h,:]·K[t,:] (16x16), softmax over t, +mask,
// out = attn@V, *0.125, then @Wp.T + b. One block per (b,s).
// ============================================================
__global__ __launch_bounds__(256) void attn_out(
    const ushort_t* __restrict__ QKV, const float* __restrict__ mask,
    const float* __restrict__ Wp, const float* __restrict__ Wpb,
    float* __restrict__ out) {
  __shared__ float Qs[16 * 68], Ks[16 * 68], Vs[16 * 68];
  __shared__ float Asc[16 * 17];
  __shared__ float Os[16 * 68];
  // stride 68 (=272B, 16B-aligned rows): projection reads WpT[e*68+tt*4+j]
  // merge into ds_read_b128 for ALL e (was: only e%4==0 at stride 65),
  // and lanes land 2-way per bank (free).
  __shared__ float WpT[64 * 68];

  const int p = blockIdx.x;
  const int t = threadIdx.x;
  const ushort_t* Qb = QKV;
  const ushort_t* Kb = QKV + (size_t)NX;
  const ushort_t* Vb = QKV + (size_t)2 * NX;
  const size_t base = (size_t)p * (H_ * DH_);

  // stage Q,K,V bf16 -> f32 LDS (padded stride 68)
  {
    const int idx = t * 4;
    const int h0 = idx >> 6, d0 = idx & 63;
    ushort4 q = *(const ushort4*)(Qb + base + idx);
    ushort4 k = *(const ushort4*)(Kb + base + idx);
    ushort4 v = *(const ushort4*)(Vb + base + idx);
    float* qd = Qs + h0 * 68 + d0;
    float* kd = Ks + h0 * 68 + d0;
    float* vd = Vs + h0 * 68 + d0;
    qd[0] = bf2f(q.x); qd[1] = bf2f(q.y); qd[2] = bf2f(q.z); qd[3] = bf2f(q.w);
    kd[0] = bf2f(k.x); kd[1] = bf2f(k.y); kd[2] = bf2f(k.z); kd[3] = bf2f(k.w);
    vd[0] = bf2f(v.x); vd[1] = bf2f(v.y); vd[2] = bf2f(v.z); vd[3] = bf2f(v.w);
  }
  // stage Wp transposed: WpT[e][d] = Wp[d][e]
#pragma unroll
  for (int i = 0; i < 16; ++i) {
    const int idx = i * 256 + t;          // 0..4095
    const int dr = idx >> 6, e = idx & 63;
    WpT[e * 68 + dr] = Wp[idx];
  }
  __syncthreads();

  const int h = t >> 4, tt = t & 15;

  // scores + softmax (16-lane-group shuffle reduce)
  float s = 0.f;
#pragma unroll
  for (int d = 0; d < 64; ++d) s += Qs[h * 68 + d] * Ks[tt * 68 + d];
  float mx = s;
#pragma unroll
  for (int o = 8; o >= 1; o >>= 1) mx = fmaxf(mx, __shfl_xor(mx, o, 16));
  const float ev = __expf(s - mx);
  float sm = ev;
#pragma unroll
  for (int o = 8; o >= 1; o >>= 1) sm += __shfl_xor(sm, o, 16);
  Asc[h * 17 + tt] = ev / sm + mask[h * 16 + tt];   // faithful quirk: mask AFTER softmax
  __syncthreads();

  // PV: out[h][d] = sum_t attn[h][t] * V[t][d]; scale AFTER (quirk)
  {
    const int dq = tt * 4;
    float4 o4 = {0.f, 0.f, 0.f, 0.f};
#pragma unroll
    for (int k = 0; k < 16; ++k) {
      const float a = Asc[h * 17 + k];
      o4.x += a * Vs[k * 68 + dq + 0];
      o4.y += a * Vs[k * 68 + dq + 1];
      o4.z += a * Vs[k * 68 + dq + 2];
      o4.w += a * Vs[k * 68 + dq + 3];
    }
    float* od = Os + h * 68 + dq;
    od[0] = o4.x * 0.125f; od[1] = o4.y * 0.125f;
    od[2] = o4.z * 0.125f; od[3] = o4.w * 0.125f;
  }
  __syncthreads();

  // projection: final[h][d] = sum_e Os[h][e] * Wp[d][e] + Wpb[d]
  {
    const int dq = tt * 4;
    float r0 = Wpb[dq + 0], r1 = Wpb[dq + 1], r2 = Wpb[dq + 2], r3 = Wpb[dq + 3];
#pragma unroll
    for (int e = 0; e < 64; ++e) {
      const float ov = Os[h * 68 + e];
      const float* wr = WpT + e * 68 + dq;
      r0 += ov * wr[0]; r1 += ov * wr[1]; r2 += ov * wr[2]; r3 += ov * wr[3];
    }
    float4 res = {r0, r1, r2, r3};
    *(float4*)(out + base + h * 64 + dq) = res;
  }
}

// ============================================================
extern "C" void kernel_launch(void* const* d_in, const int* in_sizes, int n_in,
                              void* d_out, int out_size, void* d_ws, size_t ws_size,
                              hipStream_t stream) {
  const float* target = (const float*)d_in[0];
  const float* source = (const float*)d_in[1];
  const float* memory = (const float*)d_in[2];
  const float* mask   = (const float*)d_in[3];
  const float* WQw = (const float*)d_in[4];
  const float* WQb = (const float*)d_in[5];
  const float* WKw = (const float*)d_in[6];
  const float* WKb = (const float*)d_in[7];
  const float* WVw = (const float*)d_in[8];
  const float* WVb = (const float*)d_in[9];
  const float* Wpw = (const float*)d_in[10];
  const float* Wpb = (const float*)d_in[11];

  // workspace layout (bytes): Xb 48MB | Wb 6MB | QKV 48MB  = ~102MB
  ushort_t* Xb  = (ushort_t*)d_ws;            // 3*NX bf16
  ushort_t* Wb  = Xb + (size_t)3 * NX;        // 3*NW bf16
  ushort_t* QKV = Wb + (size_t)3 * NW;        // 3*NX bf16
  float* outp = (float*)d_out;

  // A: convert inputs + weights to bf16
  cvt6<<<dim3((3 * NX / 4 + 3 * NW / 4) / 256), 256, 0, stream>>>(
      target, source, memory, WQw, WKw, WVw, Xb, Wb);

  // B: QKV projections (bias fused), bf16 out; 1D grid with T1 XCD swizzle
  gemm_qkv<<<dim3(1536), 256, 0, stream>>>(Xb, Wb, WQb, WKb, WVb, QKV);

  // C: fused head-attention + final projection, f32 out
  attn_out<<<dim3(M_), 256, 0, stream>>>(QKV, mask, Wpw, Wpb, outp);
}

// Round 12
// 284.618 us; speedup vs baseline: 1.1051x; 1.0054x over previous
//
#include <hip/hip_runtime.h>
#include <hip/hip_bf16.h>

// Problem constants
#define B_ 4
#define S_ 2048
#define D_ 1024
#define H_ 16
#define DH_ 64
#define M_ 8192                 // B*S rows
#define NX (M_ * D_)            // 8388608 elems per activation matrix
#define NW (D_ * D_)            // 1048576 elems per weight matrix

typedef unsigned short ushort_t;
typedef __attribute__((ext_vector_type(8))) short short8;   // 8 bf16 (4 VGPRs)
typedef __attribute__((ext_vector_type(4))) float f32x4;

// ---- bf16 helpers (bit-level, RNE) ----
__device__ inline float bf2f(unsigned short u) {
  union { unsigned int i; float f; } c; c.i = ((unsigned int)u) << 16; return c.f;
}
__device__ inline unsigned short f2bf(float f) {
  union { float f_; unsigned int i; } c; c.f_ = f;
  return (unsigned short)((c.i + 0x7FFFu + ((c.i >> 16) & 1u)) >> 16);
}

// ---- async global->LDS, 16B per lane ----
typedef __attribute__((address_space(1))) void v_g;
typedef __attribute__((address_space(3))) void v_l;
__device__ inline void async16(const void* g, void* l) {
  __builtin_amdgcn_global_load_lds((const v_g*)g, (v_l*)l, 16, 0, 0);
}

// ============================================================
// Kernel A: convert 3 activation mats + 3 weight mats f32->bf16
// ============================================================
__global__ __launch_bounds__(256) void cvt6(
    const float* __restrict__ x0, const float* __restrict__ x1, const float* __restrict__ x2,
    const float* __restrict__ w0, const float* __restrict__ w1, const float* __restrict__ w2,
    ushort_t* __restrict__ xb, ushort_t* __restrict__ wb) {
  const int GX = NX / 4;   // 2^21 groups of 4 floats per activation
  const int GW = NW / 4;   // 2^18 per weight
  int g = blockIdx.x * 256 + threadIdx.x;
  const float* src; ushort_t* dst; int off;
  if (g < 3 * GX) {
    int mat = g / GX; off = (g - mat * GX) * 4;
    src = (mat == 0) ? x0 : ((mat == 1) ? x1 : x2);
    dst = xb + (size_t)mat * NX;
  } else {
    int g2 = g - 3 * GX;
    if (g2 >= 3 * GW) return;
    int mat = g2 / GW; off = (g2 - mat * GW) * 4;
    src = (mat == 0) ? w0 : ((mat == 1) ? w1 : w2);
    dst = wb + (size_t)mat * NW;
  }
  float4 v = *(const float4*)(src + off);
  ushort4 o;
  o.x = f2bf(v.x); o.y = f2bf(v.y); o.z = f2bf(v.z); o.w = f2bf(v.w);
  *(ushort4*)(dst + off) = o;
}

// ============================================================
// Kernel B: C[m,n] = sum_k A[m,k]*W[n,k] + bias[n]  (bf16 MFMA)
// 128x128 tile, BK=64, 4 waves; 2-phase double-buffered LDS (T3 minimum):
// stage tile kt+1 BEFORE computing tile kt; one vmcnt(0)+barrier per step.
// grid = 1D 1536 with bijective XCD swizzle (T1).
// ============================================================
__global__ __launch_bounds__(256) void gemm_qkv(
    const ushort_t* __restrict__ Xb, const ushort_t* __restrict__ Wb,
    const float* __restrict__ bQ, const float* __restrict__ bK, const float* __restrict__ bV,
    ushort_t* __restrict__ Out) {
  __shared__ __align__(16) ushort_t As[2][128 * 64];   // 2 x 16KB
  __shared__ __align__(16) ushort_t Bs[2][128 * 64];   // 2 x 16KB

  // T1 XCD swizzle: hw block o lands on XCD (o%8); each XCD gets a
  // contiguous run of 192 logical tiles (24 A-panels, each reused 8x).
  const int o = blockIdx.x;
  const int sw = (o & 7) * 192 + (o >> 3);   // bijective on [0,1536)
  const int mat = sw >> 9;                   // 512 tiles per matrix
  const int w_  = sw & 511;
  const int tn = w_ & 7;        // N/128 = 8 col tiles (share A panel)
  const int tm = w_ >> 3;       // M/128 = 64 row tiles

  const ushort_t* A  = Xb + (size_t)mat * NX;
  const ushort_t* Bg = Wb + (size_t)mat * NW;
  const float* bias = (mat == 0) ? bQ : ((mat == 1) ? bK : bV);
  ushort_t* C = Out + (size_t)mat * NX;

  const int m0 = tm * 128, n0 = tn * 128;

  const int t = threadIdx.x;
  const int w = t >> 6, l = t & 63;
  const int wr = w >> 1, wc = w & 1;    // wave quadrant (64x64)

  // staging geometry: chunk c = i*256+t covers (row = i*32 + t>>3, col8 = (t&7)*8)
  const int r0 = t >> 3;
  const int c0 = (t & 7) << 3;
  const ushort_t* gAt = A  + (size_t)(m0 + r0) * D_ + c0;
  const ushort_t* gBt = Bg + (size_t)(n0 + r0) * D_ + c0;
  const int lofs = w * 512;             // + i*2048 per staging chunk

  // fragment read offsets (16x16x32 bf16: lane holds row l&15, k = (l>>4)*8 .. +7)
  const int lrow = l & 15, lk = (l >> 4) << 3;
  const int aoff = (wr * 64 + lrow) * 64 + lk;
  const int boff = (wc * 64 + lrow) * 64 + lk;

  f32x4 acc[4][4];
#pragma unroll
  for (int i = 0; i < 4; i++)
#pragma unroll
    for (int j = 0; j < 4; j++) acc[i][j] = (f32x4){0.f, 0.f, 0.f, 0.f};

  // prologue: stage K-tile 0 into buffer 0, drain, barrier
#pragma unroll
  for (int i = 0; i < 4; ++i) {
    async16(gAt + (size_t)i * (32 * D_), &As[0][lofs + i * 2048]);
    async16(gBt + (size_t)i * (32 * D_), &Bs[0][lofs + i * 2048]);
  }
  asm volatile("s_waitcnt vmcnt(0)" ::: "memory");
  __syncthreads();

  int cur = 0;
  for (int kt = 0; kt < 16; ++kt) {
    // phase 1: issue next tile's loads into the other buffer (overlap w/ compute)
    if (kt < 15) {
      const int k1 = (kt + 1) * 64;
      const int nxt = cur ^ 1;
#pragma unroll
      for (int i = 0; i < 4; ++i) {
        async16(gAt + (size_t)i * (32 * D_) + k1, &As[nxt][lofs + i * 2048]);
        async16(gBt + (size_t)i * (32 * D_) + k1, &Bs[nxt][lofs + i * 2048]);
      }
    }
    // phase 2: compute current tile
    const ushort_t* Ac = As[cur];
    const ushort_t* Bc = Bs[cur];
#pragma unroll
    for (int kk = 0; kk < 64; kk += 32) {
      short8 a[4], b[4];
#pragma unroll
      for (int mi = 0; mi < 4; mi++) a[mi] = *(const short8*)(Ac + aoff + mi * (16 * 64) + kk);
#pragma unroll
      for (int ni = 0; ni < 4; ni++) b[ni] = *(const short8*)(Bc + boff + ni * (16 * 64) + kk);
      __builtin_amdgcn_s_setprio(1);
#pragma unroll
      for (int mi = 0; mi < 4; mi++)
#pragma unroll
        for (int ni = 0; ni < 4; ni++)
          acc[mi][ni] = __builtin_amdgcn_mfma_f32_16x16x32_bf16(a[mi], b[ni], acc[mi][ni], 0, 0, 0);
      __builtin_amdgcn_s_setprio(0);
    }
    // phase 3: next buffer ready (loads drained), all reads of cur done
    if (kt < 15) {
      asm volatile("s_waitcnt vmcnt(0)" ::: "memory");
      __syncthreads();
      cur ^= 1;
    }
  }

  // epilogue: C/D layout col=lane&15, row=(lane>>4)*4+reg  (m89/m91-verified)
  const int crow0 = m0 + wr * 64 + ((l >> 4) << 2);
  const int ccol0 = n0 + wc * 64 + (l & 15);
#pragma unroll
  for (int mi = 0; mi < 4; mi++) {
#pragma unroll
    for (int ni = 0; ni < 4; ni++) {
      const int col = ccol0 + ni * 16;
      const float bv = bias[col];
      const int row = crow0 + mi * 16;
#pragma unroll
      for (int r = 0; r < 4; r++) {
        C[(size_t)(row + r) * D_ + col] = f2bf(acc[mi][ni][r] + bv);
      }
    }
  }
}

// ============================================================
// Kernel C: per-position head attention + output projection
// scores[h][t] = Q[h,:]·K[t,:] (16x16), softmax over t, +mask,
// out = attn@V, *0.125, then @Wp.T + b. One block per (b,s).
// ============================================================
__global__ __launch_bounds__(256) void attn_out(
    const ushort_t* __restrict__ QKV, const float* __restrict__ mask,
    const float* __restrict__ Wp, const float* __restrict__ Wpb,
    float* __restrict__ out) {
  __shared__ float Qs[16 * 68], Ks[16 * 68], Vs[16 * 68];
  __shared__ float Asc[16 * 17];
  __shared__ float Os[16 * 68];
  // stride 68 (=272B, 16B-aligned rows): projection reads WpT[e*68+tt*4+j]
  // merge into ds_read_b128 for ALL e, lanes land 2-way per bank (free).
  __shared__ float WpT[64 * 68];

  const int p = blockIdx.x;
  const int t = threadIdx.x;
  const ushort_t* Qb = QKV;
  const ushort_t* Kb = QKV + (size_t)NX;
  const ushort_t* Vb = QKV + (size_t)2 * NX;
  const size_t base = (size_t)p * (H_ * DH_);

  // stage Q,K,V bf16 -> f32 LDS (padded stride 68)
  {
    const int idx = t * 4;
    const int h0 = idx >> 6, d0 = idx & 63;
    ushort4 q = *(const ushort4*)(Qb + base + idx);
    ushort4 k = *(const ushort4*)(Kb + base + idx);
    ushort4 v = *(const ushort4*)(Vb + base + idx);
    float* qd = Qs + h0 * 68 + d0;
    float* kd = Ks + h0 * 68 + d0;
    float* vd = Vs + h0 * 68 + d0;
    qd[0] = bf2f(q.x); qd[1] = bf2f(q.y); qd[2] = bf2f(q.z); qd[3] = bf2f(q.w);
    kd[0] = bf2f(k.x); kd[1] = bf2f(k.y); kd[2] = bf2f(k.z); kd[3] = bf2f(k.w);
    vd[0] = bf2f(v.x); vd[1] = bf2f(v.y); vd[2] = bf2f(v.z); vd[3] = bf2f(v.w);
  }
  // stage Wp transposed: WpT[e][d] = Wp[d][e]
#pragma unroll
  for (int i = 0; i < 16; ++i) {
    const int idx = i * 256 + t;          // 0..4095
    const int dr = idx >> 6, e = idx & 63;
    WpT[e * 68 + dr] = Wp[idx];
  }
  __syncthreads();

  const int h = t >> 4, tt = t & 15;

  // scores + softmax (16-lane-group shuffle reduce)
  float s = 0.f;
#pragma unroll
  for (int d = 0; d < 64; ++d) s += Qs[h * 68 + d] * Ks[tt * 68 + d];
  float mx = s;
#pragma unroll
  for (int o = 8; o >= 1; o >>= 1) mx = fmaxf(mx, __shfl_xor(mx, o, 16));
  const float ev = __expf(s - mx);
  float sm = ev;
#pragma unroll
  for (int o = 8; o >= 1; o >>= 1) sm += __shfl_xor(sm, o, 16);
  Asc[h * 17 + tt] = ev / sm + mask[h * 16 + tt];   // faithful quirk: mask AFTER softmax
  __syncthreads();

  // PV: out[h][d] = sum_t attn[h][t] * V[t][d]; scale AFTER (quirk)
  {
    const int dq = tt * 4;
    float4 o4 = {0.f, 0.f, 0.f, 0.f};
#pragma unroll
    for (int k = 0; k < 16; ++k) {
      const float a = Asc[h * 17 + k];
      o4.x += a * Vs[k * 68 + dq + 0];
      o4.y += a * Vs[k * 68 + dq + 1];
      o4.z += a * Vs[k * 68 + dq + 2];
      o4.w += a * Vs[k * 68 + dq + 3];
    }
    float* od = Os + h * 68 + dq;
    od[0] = o4.x * 0.125f; od[1] = o4.y * 0.125f;
    od[2] = o4.z * 0.125f; od[3] = o4.w * 0.125f;
  }
  __syncthreads();

  // projection: final[h][d] = sum_e Os[h][e] * Wp[d][e] + Wpb[d]
  {
    const int dq = tt * 4;
    float r0 = Wpb[dq + 0], r1 = Wpb[dq + 1], r2 = Wpb[dq + 2], r3 = Wpb[dq + 3];
#pragma unroll
    for (int e = 0; e < 64; ++e) {
      const float ov = Os[h * 68 + e];
      const float* wr = WpT + e * 68 + dq;
      r0 += ov * wr[0]; r1 += ov * wr[1]; r2 += ov * wr[2]; r3 += ov * wr[3];
    }
    float4 res = {r0, r1, r2, r3};
    *(float4*)(out + base + h * 64 + dq) = res;
  }
}

// ============================================================
extern "C" void kernel_launch(void* const* d_in, const int* in_sizes, int n_in,
                              void* d_out, int out_size, void* d_ws, size_t ws_size,
                              hipStream_t stream) {
  const float* target = (const float*)d_in[0];
  const float* source = (const float*)d_in[1];
  const float* memory = (const float*)d_in[2];
  const float* mask   = (const float*)d_in[3];
  const float* WQw = (const float*)d_in[4];
  const float* WQb = (const float*)d_in[5];
  const float* WKw = (const float*)d_in[6];
  const float* WKb = (const float*)d_in[7];
  const float* WVw = (const float*)d_in[8];
  const float* WVb = (const float*)d_in[9];
  const float* Wpw = (const float*)d_in[10];
  const float* Wpb = (const float*)d_in[11];

  // workspace layout (bytes): Xb 48MB | Wb 6MB | QKV 48MB  = ~102MB
  ushort_t* Xb  = (ushort_t*)d_ws;            // 3*NX bf16
  ushort_t* Wb  = Xb + (size_t)3 * NX;        // 3*NW bf16
  ushort_t* QKV = Wb + (size_t)3 * NW;        // 3*NX bf16
  float* outp = (float*)d_out;

  // A: convert inputs + weights to bf16
  cvt6<<<dim3((3 * NX / 4 + 3 * NW / 4) / 256), 256, 0, stream>>>(
      target, source, memory, WQw, WKw, WVw, Xb, Wb);

  // B: QKV projections (bias fused), bf16 out; 2-phase dbuf + T1 XCD swizzle
  gemm_qkv<<<dim3(1536), 256, 0, stream>>>(Xb, Wb, WQb, WKb, WVb, QKV);

  // C: fused head-attention + final projection, f32 out
  attn_out<<<dim3(M_), 256, 0, stream>>>(QKV, mask, Wpw, Wpb, outp);
}